// Round 2
// baseline (4029.030 us; speedup 1.0000x reference)
//
#include <hip/hip_runtime.h>
#include <stdint.h>

typedef unsigned short u16;
typedef short bf16x8 __attribute__((ext_vector_type(8)));
typedef float f32x4 __attribute__((ext_vector_type(4)));

#define DEV static __device__ __forceinline__

constexpr int B_ = 512, T_ = 64, IN_ = 256, H_ = 512, V1_ = 101, P_ = 8, G4_ = 2048;
constexpr int EXR = 613;      // 101 embed rows + 512 x rows
constexpr int FST = 104;      // feat2 row stride (f32), 16B-aligned
constexpr int M_  = T_ * B_;  // 32768

DEV float b2f(u16 u) { union { uint32_t i; float f; } v; v.i = ((uint32_t)u) << 16; return v.f; }
DEV u16 f2b(float f) {
  union { float f; uint32_t i; } v; v.f = f;
  uint32_t i = v.i;
  return (u16)((i + 0x7fffu + ((i >> 16) & 1u)) >> 16);  // RNE
}
DEV float sigf(float x) { return 1.f / (1.f + __expf(-x)); }
DEV float tanh_(float x) {
  float c = fminf(fmaxf(x, -15.f), 15.f);
  float e = __expf(2.f * c);
  return (e - 1.f) / (e + 1.f);
}
DEV bf16x8 ld8(const u16* p) { return *reinterpret_cast<const bf16x8*>(p); }
DEV f32x4 mfma16(bf16x8 a, bf16x8 b, f32x4 c) {
  return __builtin_amdgcn_mfma_f32_16x16x32_bf16(a, b, c, 0, 0, 0);
}

// ---------------- f32 -> bf16 conversion (n must be /4) ----------------
__global__ __launch_bounds__(256) void k_cvt(const float* __restrict__ src,
                                             u16* __restrict__ dst, int n4) {
  int i = blockIdx.x * 256 + threadIdx.x;
  if (i >= n4) return;
  const float4 v = reinterpret_cast<const float4*>(src)[i];
  ushort4 o;
  o.x = f2b(v.x); o.y = f2b(v.y); o.z = f2b(v.z); o.w = f2b(v.w);
  reinterpret_cast<ushort4*>(dst)[i] = o;
}

// ---------------- EX0 = ex_src @ w_ih0^T   (613 x 2048) f32 ----------------
// ex_src: bf16 [613][256] (embed rows then x rows); wih0 f32 (2048x256) converted on the fly per-fragment
__global__ __launch_bounds__(256) void k_precomp(const u16* __restrict__ ex_src,
                                                 const u16* __restrict__ wih0b,
                                                 float* __restrict__ EX0) {
  const int lane = threadIdx.x & 63;
  const int wv = threadIdx.x >> 6;
  const int m0 = blockIdx.x * 64 + wv * 16;
  const int n0 = blockIdx.y * 64;
  const int lr = lane & 15;
  const int lk = (lane >> 4) * 8;

  const int arow = m0 + lr;
  const bool valid = arow < EXR;

  f32x4 acc[4] = {};
  for (int k0 = 0; k0 < IN_; k0 += 32) {
    bf16x8 a = {};
    if (valid) a = ld8(ex_src + (size_t)arow * IN_ + k0 + lk);
#pragma unroll
    for (int c = 0; c < 4; ++c) {
      bf16x8 b = ld8(wih0b + (size_t)(n0 + c * 16 + lr) * IN_ + k0 + lk);
      acc[c] = mfma16(a, b, acc[c]);
    }
  }
  const int rb = (lane >> 4) * 4;
#pragma unroll
  for (int c = 0; c < 4; ++c)
#pragma unroll
    for (int r = 0; r < 4; ++r) {
      int row = m0 + rb + r;
      int col = n0 + c * 16 + (lane & 15);
      if (row < EXR) EX0[(size_t)row * G4_ + col] = acc[c][r];
    }
}

// ---------------- one LSTM layer step ----------------
template <int LAYER>
__global__ __launch_bounds__(256) void k_step(
    const u16* __restrict__ hA, const u16* __restrict__ hB,
    const u16* __restrict__ W1, const u16* __restrict__ W2,
    const float* __restrict__ EX0, const int* __restrict__ y, int t,
    float* __restrict__ cst, u16* __restrict__ hout, u16* __restrict__ outs_t) {
  const int lane = threadIdx.x & 63;
  const int wv = threadIdx.x >> 6;
  const int m0 = blockIdx.x * 64 + wv * 16;  // batch rows
  const int j0 = blockIdx.y * 32;            // h-unit columns
  const int lr = lane & 15;
  const int lk = (lane >> 4) * 8;

  f32x4 acc[4][2] = {};
  {
    const u16* arow = hA + (size_t)(m0 + lr) * H_ + lk;
    const u16* wp[4][2];
#pragma unroll
    for (int g = 0; g < 4; ++g)
#pragma unroll
      for (int h = 0; h < 2; ++h)
        wp[g][h] = W1 + (size_t)(g * H_ + j0 + h * 16 + lr) * H_ + lk;
    for (int k0 = 0; k0 < H_; k0 += 32) {
      bf16x8 a = ld8(arow + k0);
#pragma unroll
      for (int g = 0; g < 4; ++g)
#pragma unroll
        for (int h = 0; h < 2; ++h)
          acc[g][h] = mfma16(a, ld8(wp[g][h] + k0), acc[g][h]);
    }
  }
  if constexpr (LAYER == 1) {
    const u16* arow = hB + (size_t)(m0 + lr) * H_ + lk;
    const u16* wp[4][2];
#pragma unroll
    for (int g = 0; g < 4; ++g)
#pragma unroll
      for (int h = 0; h < 2; ++h)
        wp[g][h] = W2 + (size_t)(g * H_ + j0 + h * 16 + lr) * H_ + lk;
    for (int k0 = 0; k0 < H_; k0 += 32) {
      bf16x8 a = ld8(arow + k0);
#pragma unroll
      for (int g = 0; g < 4; ++g)
#pragma unroll
        for (int h = 0; h < 2; ++h)
          acc[g][h] = mfma16(a, ld8(wp[g][h] + k0), acc[g][h]);
    }
  }

  const int rb = (lane >> 4) * 4;
#pragma unroll
  for (int h = 0; h < 2; ++h) {
    const int col = j0 + h * 16 + (lane & 15);
#pragma unroll
    for (int r = 0; r < 4; ++r) {
      const int row = m0 + rb + r;
      float iv = acc[0][h][r], fv = acc[1][h][r], gv = acc[2][h][r], ov = acc[3][h][r];
      if constexpr (LAYER == 0) {
        const int srow = (t == 0) ? (V1_ + row) : y[row * T_ + (t - 1)];
        const float* bp = EX0 + (size_t)srow * G4_ + col;
        iv += bp[0]; fv += bp[H_]; gv += bp[2 * H_]; ov += bp[3 * H_];
      }
      const size_t off = (size_t)row * H_ + col;
      float c = cst[off];
      float cn = sigf(fv) * c + sigf(iv) * tanh_(gv);
      float hn = sigf(ov) * tanh_(cn);
      cst[off] = cn;
      u16 hb = f2b(hn);
      hout[off] = hb;
      if constexpr (LAYER == 1) outs_t[off] = hb;
    }
  }
}

// ---------------- C = relu(A @ W^T + bias), bf16 A/W, f32 bias, bf16 out ----------------
__global__ __launch_bounds__(256) void k_gemm_relu(const u16* __restrict__ A,
                                                   const u16* __restrict__ W,
                                                   const float* __restrict__ bias,
                                                   u16* __restrict__ C) {
  const int lane = threadIdx.x & 63;
  const int wv = threadIdx.x >> 6;
  const int m0 = blockIdx.x * 64 + wv * 16;
  const int n0 = blockIdx.y * 64;
  const int lr = lane & 15;
  const int lk = (lane >> 4) * 8;

  f32x4 acc[4] = {};
  const u16* arow = A + (size_t)(m0 + lr) * H_ + lk;
  for (int k0 = 0; k0 < H_; k0 += 32) {
    bf16x8 a = ld8(arow + k0);
#pragma unroll
    for (int c = 0; c < 4; ++c) {
      bf16x8 b = ld8(W + (size_t)(n0 + c * 16 + lr) * H_ + k0 + lk);
      acc[c] = mfma16(a, b, acc[c]);
    }
  }
  const int rb = (lane >> 4) * 4;
#pragma unroll
  for (int c = 0; c < 4; ++c) {
    const int col = n0 + c * 16 + (lane & 15);
    const float bv = bias[col];
#pragma unroll
    for (int r = 0; r < 4; ++r) {
      const int row = m0 + rb + r;
      float v = acc[c][r] + bv;
      C[(size_t)row * H_ + col] = f2b(fmaxf(v, 0.f));
    }
  }
}

// ---------------- feat2 = feat1 @ l2w^T + l2b, N=101, f32 out (stride FST) ----------------
__global__ __launch_bounds__(256) void k_feat2(const u16* __restrict__ A,
                                               const u16* __restrict__ W,
                                               const float* __restrict__ bias,
                                               float* __restrict__ C) {
  const int lane = threadIdx.x & 63;
  const int wv = threadIdx.x >> 6;
  const int m0 = blockIdx.x * 64 + wv * 16;
  const int lr = lane & 15;
  const int lk = (lane >> 4) * 8;

  f32x4 acc[7] = {};
  const u16* arow = A + (size_t)(m0 + lr) * H_ + lk;
  for (int k0 = 0; k0 < H_; k0 += 32) {
    bf16x8 a = ld8(arow + k0);
#pragma unroll
    for (int c = 0; c < 7; ++c) {
      const int n = c * 16 + lr;
      bf16x8 b = {};
      if (n < V1_) b = ld8(W + (size_t)n * H_ + k0 + lk);
      acc[c] = mfma16(a, b, acc[c]);
    }
  }
  const int rb = (lane >> 4) * 4;
#pragma unroll
  for (int c = 0; c < 7; ++c) {
    const int col = c * 16 + (lane & 15);
    if (col < V1_) {
      const float bv = bias[col];
#pragma unroll
      for (int r = 0; r < 4; ++r) {
        const int row = m0 + rb + r;
        C[(size_t)row * FST + col] = acc[c][r] + bv;
      }
    }
  }
}

// ---------------- fused log_softmax (f32 -> d_out) + softmax (f32 in-place) ----------------
__global__ __launch_bounds__(256) void k_softmax(float* __restrict__ feat2,
                                                 float* __restrict__ pgm_out) {
  const int lane = threadIdx.x & 63;
  const int wv = threadIdx.x >> 6;
  const int m = blockIdx.x * 4 + wv;
  float* row = feat2 + (size_t)m * FST;
  float v1 = row[lane];
  float v2 = (lane + 64 < V1_) ? row[lane + 64] : -1e30f;
  float mx = fmaxf((lane < V1_) ? v1 : -1e30f, v2);
#pragma unroll
  for (int o = 1; o < 64; o <<= 1) mx = fmaxf(mx, __shfl_xor(mx, o, 64));
  float e1 = (lane < V1_) ? __expf(v1 - mx) : 0.f;
  float e2 = (lane + 64 < V1_) ? __expf(v2 - mx) : 0.f;
  float s = e1 + e2;
#pragma unroll
  for (int o = 1; o < 64; o <<= 1) s += __shfl_xor(s, o, 64);
  const float lz = __logf(s);
  const float inv = 1.f / s;
  const int t = m >> 9;     // m = t*B + b
  const int b = m & 511;
  float* po = pgm_out + ((size_t)b * T_ + t) * V1_;
  if (lane < V1_)      { po[lane]      = v1 - mx - lz; row[lane]      = e1 * inv; }
  if (lane + 64 < V1_) { po[lane + 64] = v2 - mx - lz; row[lane + 64] = e2 * inv; }
}

// ---------------- param[t,b,p] = concat(trans,pf1) . r2w[idx*8+p] + r2b ----------------
__global__ __launch_bounds__(256) void k_param(const float* __restrict__ trans,
                                               const u16* __restrict__ pf1,
                                               const float* __restrict__ r2w,
                                               const float* __restrict__ r2b,
                                               const int* __restrict__ y,
                                               float* __restrict__ out_par) {
  const int lane = threadIdx.x & 63;
  const int wv = threadIdx.x >> 6;
  const int m = blockIdx.x * 4 + wv;
  const int t = m >> 9;
  const int b = m & 511;
  const int idx = y[b * T_ + t];
  const float* wbase = r2w + (size_t)idx * P_ * 613;

  float a8[P_] = {};
  for (int k = lane; k < 613; k += 64) {
    float xv = (k < V1_) ? trans[(size_t)m * FST + k] : b2f(pf1[(size_t)m * H_ + (k - V1_)]);
#pragma unroll
    for (int p = 0; p < P_; ++p) a8[p] += xv * wbase[(size_t)p * 613 + k];
  }
#pragma unroll
  for (int p = 0; p < P_; ++p)
#pragma unroll
    for (int o = 1; o < 64; o <<= 1) a8[p] += __shfl_xor(a8[p], o, 64);
  if (lane < P_) {
    float v = a8[lane] + r2b[idx * P_ + lane];
    out_par[((size_t)b * T_ + t) * P_ + lane] = v;
  }
}

extern "C" void kernel_launch(void* const* d_in, const int* in_sizes, int n_in,
                              void* d_out, int out_size, void* d_ws, size_t ws_size,
                              hipStream_t stream) {
  (void)in_sizes; (void)n_in; (void)out_size; (void)ws_size;
  const float* x     = (const float*)d_in[0];
  const int*   y     = (const int*)d_in[1];
  const float* embed = (const float*)d_in[2];
  const float* wih0  = (const float*)d_in[3];
  const float* whh0  = (const float*)d_in[4];
  const float* wih1  = (const float*)d_in[5];
  const float* whh1  = (const float*)d_in[6];
  const float* l1w   = (const float*)d_in[7];
  const float* l1b   = (const float*)d_in[8];
  const float* l2w   = (const float*)d_in[9];
  const float* l2b   = (const float*)d_in[10];
  const float* r1w   = (const float*)d_in[11];
  const float* r1b   = (const float*)d_in[12];
  const float* r2w   = (const float*)d_in[13];
  const float* r2b   = (const float*)d_in[14];

  float* out_pgm = (float*)d_out;
  float* out_par = out_pgm + (size_t)B_ * T_ * V1_;

  char* ws = (char*)d_ws;
  size_t off = 0;
  auto alloc = [&](size_t bytes) { void* p = ws + off; off += (bytes + 255) & ~(size_t)255; return p; };

  float* EX0   = (float*)alloc((size_t)EXR * G4_ * 4);
  float* c0    = (float*)alloc((size_t)B_ * H_ * 4);
  float* c1    = (float*)alloc((size_t)B_ * H_ * 4);
  u16* h0_0    = (u16*)alloc((size_t)B_ * H_ * 2);
  u16* h1_0    = (u16*)alloc((size_t)B_ * H_ * 2);
  u16* h0_1    = (u16*)alloc((size_t)B_ * H_ * 2);
  u16* h1_1    = (u16*)alloc((size_t)B_ * H_ * 2);
  u16* ex_src  = (u16*)alloc((size_t)EXR * IN_ * 2);          // [embed; x] bf16
  u16* wih0b   = (u16*)alloc((size_t)4 * H_ * IN_ * 2);
  u16* whh0b   = (u16*)alloc((size_t)4 * H_ * H_ * 2);
  u16* wih1b   = (u16*)alloc((size_t)4 * H_ * H_ * 2);
  u16* whh1b   = (u16*)alloc((size_t)4 * H_ * H_ * 2);
  u16* l1wb    = (u16*)alloc((size_t)H_ * H_ * 2);
  u16* r1wb    = (u16*)alloc((size_t)H_ * H_ * 2);
  u16* l2wb    = (u16*)alloc((size_t)V1_ * H_ * 2);
  u16* outs    = (u16*)alloc((size_t)M_ * H_ * 2);
  u16* feat1   = (u16*)alloc((size_t)M_ * H_ * 2);
  u16* pf1     = (u16*)alloc((size_t)M_ * H_ * 2);
  float* feat2 = (float*)alloc((size_t)M_ * FST * 4);

  // zero: c0, c1, h0_0, h1_0 (contiguous, all sizes multiple of 256B)
  hipMemsetAsync(c0, 0, (size_t)B_ * H_ * 4 * 2 + (size_t)B_ * H_ * 2 * 2, stream);

  auto cvt = [&](const float* s, u16* d, int n) {
    int n4 = n / 4;
    k_cvt<<<(n4 + 255) / 256, 256, 0, stream>>>(s, d, n4);
  };
  cvt(embed, ex_src, V1_ * IN_);
  cvt(x, ex_src + (size_t)V1_ * IN_, B_ * IN_);
  cvt(wih0, wih0b, 4 * H_ * IN_);
  cvt(whh0, whh0b, 4 * H_ * H_);
  cvt(wih1, wih1b, 4 * H_ * H_);
  cvt(whh1, whh1b, 4 * H_ * H_);
  cvt(l1w, l1wb, H_ * H_);
  cvt(r1w, r1wb, H_ * H_);
  cvt(l2w, l2wb, V1_ * H_);

  k_precomp<<<dim3(10, 32), 256, 0, stream>>>(ex_src, wih0b, EX0);

  u16* h0[2] = {h0_0, h0_1};
  u16* h1[2] = {h1_0, h1_1};
  for (int t = 0; t < T_; ++t) {
    int p = t & 1;
    k_step<0><<<dim3(8, 16), 256, 0, stream>>>(h0[p], nullptr, whh0b, nullptr, EX0, y, t,
                                               c0, h0[p ^ 1], nullptr);
    k_step<1><<<dim3(8, 16), 256, 0, stream>>>(h0[p ^ 1], h1[p], wih1b, whh1b, EX0, y, t,
                                               c1, h1[p ^ 1], outs + (size_t)t * B_ * H_);
  }

  k_gemm_relu<<<dim3(512, 8), 256, 0, stream>>>(outs, l1wb, l1b, feat1);
  k_gemm_relu<<<dim3(512, 8), 256, 0, stream>>>(outs, r1wb, r1b, pf1);
  k_feat2<<<dim3(512, 1), 256, 0, stream>>>(feat1, l2wb, l2b, feat2);
  k_softmax<<<dim3(8192), 256, 0, stream>>>(feat2, out_pgm);
  k_param<<<dim3(8192), 256, 0, stream>>>(feat2, pf1, r2w, r2b, y, out_par);
}